// Round 9
// baseline (422.451 us; speedup 1.0000x reference)
//
#include <hip/hip_runtime.h>

#define N_NODES 10000
#define N_EDGES 320000
#define NE_TOT  330000   /* E + N */
#define NEG_SLOPE 0.2f
#define LN_EPS 1e-5f

/* workspace layout (bytes) */
#define OFF_CNT    0u          /* int[N]             */
#define OFF_FILL   40000u      /* int[~N]            */
#define OFF_ROWPTR 80128u      /* int[N+1]           */
#define OFF_EIDS   120192u     /* int[E+N]           */
#define OFF_SRCS   1440192u    /* int[E+N]           */
#define OFF_DSTS   2760192u    /* int[E+N]           */
#define OFF_LATTR  4080192u    /* float[N*64] (path B) */
#define OFF_XLH    6640192u    /* ushort[N*256] bf16 */
#define OFF_XRH    11760192u   /* ushort[N*256] bf16 */
#define OFF_LOG    16880192u   /* float[(E+N)*4] by CSR position */
#define OFF_WLF    22160192u   /* ushort[8192*8]     */
#define OFF_WRF    22291264u   /* ushort[8192*8]     */
#define OFF_INV    22422336u   /* int[E+N]  (path A) */
#define OFF_EAP    23742336u   /* ushort[(E+N)*64] bf16, CSR order (path A) */
#define WS_NEED_A  65982336u

typedef __bf16 bf16x8 __attribute__((ext_vector_type(8)));
typedef float  f32x4  __attribute__((ext_vector_type(4)));
typedef unsigned short us4 __attribute__((ext_vector_type(4)));
typedef unsigned short us8 __attribute__((ext_vector_type(8)));

__device__ __forceinline__ float bf2f(unsigned short u) {
    union { unsigned int i; float f; } v;
    v.i = ((unsigned int)u) << 16;
    return v.f;
}
__device__ __forceinline__ unsigned short f2bf(float x) {
    __bf16 b = (__bf16)x;
    return __builtin_bit_cast(unsigned short, b);
}
__device__ __forceinline__ bf16x8 cvt8(const float* p) {
    float4 v0 = *reinterpret_cast<const float4*>(p);
    float4 v1 = *reinterpret_cast<const float4*>(p + 4);
    bf16x8 t;
    t[0] = (__bf16)v0.x; t[1] = (__bf16)v0.y; t[2] = (__bf16)v0.z; t[3] = (__bf16)v0.w;
    t[4] = (__bf16)v1.x; t[5] = (__bf16)v1.y; t[6] = (__bf16)v1.z; t[7] = (__bf16)v1.w;
    return t;
}

__global__ void k_count(const int* __restrict__ ei, int* __restrict__ cnt) {
    int e = blockIdx.x * blockDim.x + threadIdx.x;
    if (e < N_EDGES) atomicAdd(&cnt[ei[N_EDGES + e]], 1);
}

__global__ void k_scan(const int* __restrict__ cnt, int* __restrict__ row_ptr) {
    __shared__ int sums[1024];
    int t = threadIdx.x;
    const int CH = 10;
    int base = t * CH;
    int s = 0;
    for (int i = 0; i < CH; i++) {
        int n = base + i;
        if (n < N_NODES) s += cnt[n] + 1;   /* +1 self loop */
    }
    sums[t] = s;
    __syncthreads();
    for (int off = 1; off < 1024; off <<= 1) {
        int v = (t >= off) ? sums[t - off] : 0;
        __syncthreads();
        sums[t] += v;
        __syncthreads();
    }
    int run = (t == 0) ? 0 : sums[t - 1];
    for (int i = 0; i < CH; i++) {
        int n = base + i;
        if (n < N_NODES) { row_ptr[n] = run; run += cnt[n] + 1; }
    }
    if (t == 1023) row_ptr[N_NODES] = sums[1023];
}

/* CSR fill + one-hop src/dst arrays + inverse permutation */
__global__ void k_fill(const int* __restrict__ ei, const int* __restrict__ row_ptr,
                       int* __restrict__ fill, int* __restrict__ eids,
                       int* __restrict__ srcs, int* __restrict__ dsts,
                       int* __restrict__ inv) {
    int e = blockIdx.x * blockDim.x + threadIdx.x;
    if (e >= NE_TOT) return;
    int s, d;
    if (e < N_EDGES) { s = ei[e]; d = ei[N_EDGES + e]; }
    else             { s = e - N_EDGES; d = s; }
    int pos = atomicAdd(&fill[d], 1);
    int p = row_ptr[d] + pos;
    eids[p] = e;
    srcs[p] = s;
    dsts[p] = d;
    inv[e] = p;
}

/* Path A: permute edge_attr into CSR order as bf16 (sequential read,
   full-line 128B scattered writes). */
__global__ void k_perm_ea(const float* __restrict__ edge_attr,
                          const int* __restrict__ inv,
                          unsigned short* __restrict__ eap) {
    int e = blockIdx.x * 4 + (threadIdx.x >> 6);
    int lane = threadIdx.x & 63;
    if (e >= N_EDGES) return;
    float v = edge_attr[(size_t)e * 64 + lane];
    eap[(size_t)inv[e] * 64 + lane] = f2bf(v);
}

/* Path A: self-loop row = mean of segment's real rows (sequential, L3-hot). */
__global__ void k_selfmean(const int* __restrict__ row_ptr,
                           const int* __restrict__ eids,
                           unsigned short* __restrict__ eap) {
    int node = (blockIdx.x << 2) + (threadIdx.x >> 6);
    int lane = threadIdx.x & 63;
    int b = row_ptr[node], en = row_ptr[node + 1];
    float s = 0.0f;
    int selfpos = b;
    for (int i = b; i < en; i++) {
        int e = eids[i];
        bool real = (e < N_EDGES);
        unsigned short u = eap[(size_t)i * 64 + lane];
        s += real ? bf2f(u) : 0.0f;
        selfpos = real ? selfpos : i;
    }
    float c = (float)(en - b - 1);
    eap[(size_t)selfpos * 64 + lane] = f2bf(s / fmaxf(c, 1.0f));
}

/* Path B: mean of incoming edge_attr into lattr (fp32). */
__global__ void k_loop_attr(const float* __restrict__ edge_attr,
                            const int* __restrict__ row_ptr,
                            const int* __restrict__ eids,
                            float* __restrict__ lattr) {
    int node = (blockIdx.x << 2) + (threadIdx.x >> 6);
    int lane = threadIdx.x & 63;
    int b = row_ptr[node], en = row_ptr[node + 1];
    float s0 = 0.0f, s1 = 0.0f, s2 = 0.0f, s3 = 0.0f;
    int i = b;
    for (; i + 3 < en; i += 4) {
        int e0 = eids[i], e1 = eids[i + 1], e2 = eids[i + 2], e3 = eids[i + 3];
        int v0 = e0 < N_EDGES, v1 = e1 < N_EDGES, v2 = e2 < N_EDGES, v3 = e3 < N_EDGES;
        float a0 = edge_attr[(size_t)(v0 ? e0 : 0) * 64 + lane];
        float a1 = edge_attr[(size_t)(v1 ? e1 : 0) * 64 + lane];
        float a2 = edge_attr[(size_t)(v2 ? e2 : 0) * 64 + lane];
        float a3 = edge_attr[(size_t)(v3 ? e3 : 0) * 64 + lane];
        s0 += v0 ? a0 : 0.0f;
        s1 += v1 ? a1 : 0.0f;
        s2 += v2 ? a2 : 0.0f;
        s3 += v3 ? a3 : 0.0f;
    }
    for (; i < en; i++) {
        int e = eids[i];
        int v = e < N_EDGES;
        float a = edge_attr[(size_t)(v ? e : 0) * 64 + lane];
        s0 += v ? a : 0.0f;
    }
    float s = (s0 + s1) + (s2 + s3);
    float c = (float)(en - b - 1);
    lattr[node * 64 + lane] = s / fmaxf(c, 1.0f);
}

/* Wl/Wr -> bf16 MFMA A-fragment order. */
__global__ void k_prep_wfrag(const float* __restrict__ Wl,
                             const float* __restrict__ Wr,
                             unsigned short* __restrict__ wlf,
                             unsigned short* __restrict__ wrf) {
    int idx = blockIdx.x * 256 + threadIdx.x;
    if (idx >= 8192) return;
    int ln = idx & 63;
    int ts = (idx >> 6) & 7;
    int ct = idx >> 9;
    int c = ct * 16 + (ln & 15);
    int k0 = ts * 32 + (ln >> 4) * 8;
    *reinterpret_cast<bf16x8*>(wlf + (size_t)idx * 8) = cvt8(Wl + (size_t)c * 256 + k0);
    *reinterpret_cast<bf16x8*>(wrf + (size_t)idx * 8) = cvt8(Wr + (size_t)c * 256 + k0);
}

/* xl/xr projection on MFMA (block = 16 nodes, 4 waves). */
__global__ __launch_bounds__(256) void k_gemm_mfma(
        const float* __restrict__ x,
        const float* __restrict__ bl, const float* __restrict__ br,
        const unsigned short* __restrict__ wlf,
        const unsigned short* __restrict__ wrf,
        unsigned short* __restrict__ xlh,
        unsigned short* __restrict__ xrh) {
    __shared__ __bf16 xs[8 * 64 * 8];
    int tid = threadIdx.x;
    int nb = blockIdx.x * 16;

    for (int f = tid; f < 512; f += 256) {
        int t = f >> 6, ln = f & 63;
        int node = nb + (ln & 15);
        int k0 = t * 32 + (ln >> 4) * 8;
        *reinterpret_cast<bf16x8*>(&xs[f * 8]) = cvt8(x + (size_t)node * 256 + k0);
    }
    __syncthreads();

    int lane = tid & 63;
    int wv = tid >> 6;
    int quad = lane >> 4;
    int ln15 = lane & 15;

    bf16x8 bfr[8];
#pragma unroll
    for (int t = 0; t < 8; t++)
        bfr[t] = *reinterpret_cast<const bf16x8*>(&xs[(t * 64 + lane) * 8]);

    int node = nb + ln15;
#pragma unroll
    for (int ci = 0; ci < 4; ci++) {
        int ct = wv * 4 + ci;
        f32x4 accl, accr;
        accl[0] = accl[1] = accl[2] = accl[3] = 0.0f;
        accr[0] = accr[1] = accr[2] = accr[3] = 0.0f;
#pragma unroll
        for (int t = 0; t < 8; t++) {
            bf16x8 al = *reinterpret_cast<const bf16x8*>(
                wlf + ((size_t)(ct * 8 + t) * 64 + lane) * 8);
            accl = __builtin_amdgcn_mfma_f32_16x16x32_bf16(al, bfr[t], accl, 0, 0, 0);
        }
#pragma unroll
        for (int t = 0; t < 8; t++) {
            bf16x8 ar = *reinterpret_cast<const bf16x8*>(
                wrf + ((size_t)(ct * 8 + t) * 64 + lane) * 8);
            accr = __builtin_amdgcn_mfma_f32_16x16x32_bf16(ar, bfr[t], accr, 0, 0, 0);
        }
        int cbase = ct * 16 + quad * 4;
        float4 blv = *reinterpret_cast<const float4*>(bl + cbase);
        float4 brv = *reinterpret_cast<const float4*>(br + cbase);
        us4 ol, orr;
        ol[0] = f2bf(accl[0] + blv.x); ol[1] = f2bf(accl[1] + blv.y);
        ol[2] = f2bf(accl[2] + blv.z); ol[3] = f2bf(accl[3] + blv.w);
        orr[0] = f2bf(accr[0] + brv.x); orr[1] = f2bf(accr[1] + brv.y);
        orr[2] = f2bf(accr[2] + brv.z); orr[3] = f2bf(accr[3] + brv.w);
        *reinterpret_cast<us4*>(xlh + (size_t)node * 256 + cbase) = ol;
        *reinterpret_cast<us4*>(xrh + (size_t)node * 256 + cbase) = orr;
    }
}

/* logits via operand-swapped 16x16x32 MFMA; CSR-ordered tiles.
   USE_EAP: ea read sequentially as prepacked bf16 (no cvt, no indirection). */
template <bool USE_EAP>
__global__ __launch_bounds__(256) void k_logits_mfma(
        const int* __restrict__ srcs, const int* __restrict__ dsts,
        const unsigned short* __restrict__ eap,
        const int* __restrict__ eids,
        const float* __restrict__ edge_attr,
        const float* __restrict__ lattr,
        const unsigned short* __restrict__ xlh,
        const unsigned short* __restrict__ xrh,
        const float* __restrict__ We, const float* __restrict__ att,
        float* __restrict__ logits) {
    __shared__ __bf16 fb[32 * 64 * 8];
    __shared__ float att_s[256];
    int tid = threadIdx.x;

    for (int idx = tid; idx < 2048; idx += 256) {
        int f = idx >> 6, ls = idx & 63;
        int cb = f >> 1, step = f & 1;
        int c = cb * 16 + (ls & 15);
        int k = step * 32 + (ls >> 4) * 8;
        *reinterpret_cast<bf16x8*>(&fb[idx * 8]) = cvt8(We + (size_t)c * 64 + k);
    }
    if (tid < 64) {
        reinterpret_cast<float4*>(att_s)[tid] =
            reinterpret_cast<const float4*>(att)[tid];
    }
    __syncthreads();

    int lane = tid & 63;
    int wv = tid >> 6;
    int quad = lane >> 4;
    int ln15 = lane & 15;

    const int ntiles = NE_TOT / 16;
    for (int t = blockIdx.x * 4 + wv; t < ntiles; t += gridDim.x * 4) {
        int pos = t * 16 + ln15;
        int s = srcs[pos];
        int d = dsts[pos];

        bf16x8 bfr[2];
        if (USE_EAP) {
            const unsigned short* er = eap + (size_t)pos * 64 + quad * 8;
            bfr[0] = __builtin_bit_cast(bf16x8, *reinterpret_cast<const us8*>(er));
            bfr[1] = __builtin_bit_cast(bf16x8, *reinterpret_cast<const us8*>(er + 32));
        } else {
            int e = eids[pos];
            const float* row = (e < N_EDGES)
                ? edge_attr + (size_t)e * 64
                : lattr + (size_t)(e - N_EDGES) * 64;
            bfr[0] = cvt8(row + quad * 8);
            bfr[1] = cvt8(row + 32 + quad * 8);
        }

        const unsigned short* xls = xlh + (size_t)s * 256;
        const unsigned short* xrd = xrh + (size_t)d * 256;

        float hsum[4] = {0.0f, 0.0f, 0.0f, 0.0f};
#pragma unroll 4
        for (int cb = 0; cb < 16; cb++) {
            f32x4 acc;
            acc[0] = acc[1] = acc[2] = acc[3] = 0.0f;
            bf16x8 a0 = *reinterpret_cast<const bf16x8*>(&fb[((cb * 2 + 0) * 64 + lane) * 8]);
            bf16x8 a1 = *reinterpret_cast<const bf16x8*>(&fb[((cb * 2 + 1) * 64 + lane) * 8]);
            acc = __builtin_amdgcn_mfma_f32_16x16x32_bf16(a0, bfr[0], acc, 0, 0, 0);
            acc = __builtin_amdgcn_mfma_f32_16x16x32_bf16(a1, bfr[1], acc, 0, 0, 0);

            int cbase = cb * 16 + quad * 4;
            us4 xa = *reinterpret_cast<const us4*>(xls + cbase);
            us4 xb = *reinterpret_cast<const us4*>(xrd + cbase);
            float4 at = *reinterpret_cast<const float4*>(&att_s[cbase]);
            const float* tp = reinterpret_cast<const float*>(&at);
            float hs = 0.0f;
#pragma unroll
            for (int r = 0; r < 4; r++) {
                float v = acc[r] + bf2f(xa[r]) + bf2f(xb[r]);
                v = (v >= 0.0f) ? v : NEG_SLOPE * v;
                hs = fmaf(v, tp[r], hs);
            }
            hsum[cb >> 2] += hs;
        }
#pragma unroll
        for (int hh = 0; hh < 4; hh++) {
            hsum[hh] += __shfl_xor(hsum[hh], 16, 64);
            hsum[hh] += __shfl_xor(hsum[hh], 32, 64);
        }
        if (quad == 0) {
            reinterpret_cast<float4*>(logits)[pos] =
                make_float4(hsum[0], hsum[1], hsum[2], hsum[3]);
        }
    }
}

/* wave per node: softmax + weighted sum + bias + SiLU + LayerNorm.
   srcs[] gives one-hop gather index (no eids->ei chain). */
__global__ void k_aggregate(const int* __restrict__ row_ptr,
                            const int* __restrict__ eids,
                            const int* __restrict__ srcs,
                            const float* __restrict__ logits,
                            const unsigned short* __restrict__ xlh,
                            const float* __restrict__ bias,
                            const float* __restrict__ gamma,
                            const float* __restrict__ beta,
                            float* __restrict__ hout,
                            float* __restrict__ alpha_out) {
    int node = (blockIdx.x << 2) + (threadIdx.x >> 6);
    int lane = threadIdx.x & 63;
    int h = lane >> 4;
    int b = row_ptr[node], en = row_ptr[node + 1];

    float m0 = -INFINITY, m1 = -INFINITY, m2 = -INFINITY, m3 = -INFINITY;
    int i = b;
    for (; i + 3 < en; i += 4) {
        m0 = fmaxf(m0, logits[(i + 0) * 4 + h]);
        m1 = fmaxf(m1, logits[(i + 1) * 4 + h]);
        m2 = fmaxf(m2, logits[(i + 2) * 4 + h]);
        m3 = fmaxf(m3, logits[(i + 3) * 4 + h]);
    }
    for (; i < en; i++) m0 = fmaxf(m0, logits[i * 4 + h]);
    float mh = fmaxf(fmaxf(m0, m1), fmaxf(m2, m3));

    float d0 = 0.0f, d1 = 0.0f, d2 = 0.0f, d3 = 0.0f;
    i = b;
    for (; i + 3 < en; i += 4) {
        d0 += __expf(logits[(i + 0) * 4 + h] - mh);
        d1 += __expf(logits[(i + 1) * 4 + h] - mh);
        d2 += __expf(logits[(i + 2) * 4 + h] - mh);
        d3 += __expf(logits[(i + 3) * 4 + h] - mh);
    }
    for (; i < en; i++) d0 += __expf(logits[i * 4 + h] - mh);
    float rden = 1.0f / ((d0 + d1) + (d2 + d3));

    int c0 = lane * 4;
    float4 ac0; ac0.x = ac0.y = ac0.z = ac0.w = 0.0f;
    float4 ac1; ac1.x = ac1.y = ac1.z = ac1.w = 0.0f;
    float4 ac2; ac2.x = ac2.y = ac2.z = ac2.w = 0.0f;
    float4 ac3; ac3.x = ac3.y = ac3.z = ac3.w = 0.0f;
    i = b;
    for (; i + 3 < en; i += 4) {
        int e0 = eids[i], e1 = eids[i + 1], e2 = eids[i + 2], e3 = eids[i + 3];
        int s0 = srcs[i], s1 = srcs[i + 1], s2 = srcs[i + 2], s3 = srcs[i + 3];
        float al0 = __expf(logits[(i + 0) * 4 + h] - mh) * rden;
        float al1 = __expf(logits[(i + 1) * 4 + h] - mh) * rden;
        float al2 = __expf(logits[(i + 2) * 4 + h] - mh) * rden;
        float al3 = __expf(logits[(i + 3) * 4 + h] - mh) * rden;
        if ((lane & 15) == 0) {
            alpha_out[e0 * 4 + h] = al0;
            alpha_out[e1 * 4 + h] = al1;
            alpha_out[e2 * 4 + h] = al2;
            alpha_out[e3 * 4 + h] = al3;
        }
        us4 x0 = *reinterpret_cast<const us4*>(xlh + (size_t)s0 * 256 + c0);
        us4 x1 = *reinterpret_cast<const us4*>(xlh + (size_t)s1 * 256 + c0);
        us4 x2 = *reinterpret_cast<const us4*>(xlh + (size_t)s2 * 256 + c0);
        us4 x3 = *reinterpret_cast<const us4*>(xlh + (size_t)s3 * 256 + c0);
        ac0.x = fmaf(al0, bf2f(x0[0]), ac0.x); ac0.y = fmaf(al0, bf2f(x0[1]), ac0.y);
        ac0.z = fmaf(al0, bf2f(x0[2]), ac0.z); ac0.w = fmaf(al0, bf2f(x0[3]), ac0.w);
        ac1.x = fmaf(al1, bf2f(x1[0]), ac1.x); ac1.y = fmaf(al1, bf2f(x1[1]), ac1.y);
        ac1.z = fmaf(al1, bf2f(x1[2]), ac1.z); ac1.w = fmaf(al1, bf2f(x1[3]), ac1.w);
        ac2.x = fmaf(al2, bf2f(x2[0]), ac2.x); ac2.y = fmaf(al2, bf2f(x2[1]), ac2.y);
        ac2.z = fmaf(al2, bf2f(x2[2]), ac2.z); ac2.w = fmaf(al2, bf2f(x2[3]), ac2.w);
        ac3.x = fmaf(al3, bf2f(x3[0]), ac3.x); ac3.y = fmaf(al3, bf2f(x3[1]), ac3.y);
        ac3.z = fmaf(al3, bf2f(x3[2]), ac3.z); ac3.w = fmaf(al3, bf2f(x3[3]), ac3.w);
    }
    for (; i < en; i++) {
        int e = eids[i];
        int s = srcs[i];
        float al = __expf(logits[i * 4 + h] - mh) * rden;
        if ((lane & 15) == 0) alpha_out[e * 4 + h] = al;
        us4 xv = *reinterpret_cast<const us4*>(xlh + (size_t)s * 256 + c0);
        ac0.x = fmaf(al, bf2f(xv[0]), ac0.x); ac0.y = fmaf(al, bf2f(xv[1]), ac0.y);
        ac0.z = fmaf(al, bf2f(xv[2]), ac0.z); ac0.w = fmaf(al, bf2f(xv[3]), ac0.w);
    }
    float4 acc;
    acc.x = (ac0.x + ac1.x) + (ac2.x + ac3.x);
    acc.y = (ac0.y + ac1.y) + (ac2.y + ac3.y);
    acc.z = (ac0.z + ac1.z) + (ac2.z + ac3.z);
    acc.w = (ac0.w + ac1.w) + (ac2.w + ac3.w);

    const float4 b4 = reinterpret_cast<const float4*>(bias)[lane];
    float4 hv;
    hv.x = acc.x + b4.x; hv.y = acc.y + b4.y;
    hv.z = acc.z + b4.z; hv.w = acc.w + b4.w;
    hv.x = hv.x / (1.0f + __expf(-hv.x));
    hv.y = hv.y / (1.0f + __expf(-hv.y));
    hv.z = hv.z / (1.0f + __expf(-hv.z));
    hv.w = hv.w / (1.0f + __expf(-hv.w));
    float s1 = hv.x + hv.y + hv.z + hv.w;
    float s2 = hv.x * hv.x + hv.y * hv.y + hv.z * hv.z + hv.w * hv.w;
#pragma unroll
    for (int off = 1; off < 64; off <<= 1) {
        s1 += __shfl_xor(s1, off, 64);
        s2 += __shfl_xor(s2, off, 64);
    }
    float mu = s1 * (1.0f / 256.0f);
    float var = s2 * (1.0f / 256.0f) - mu * mu;
    float rs = rsqrtf(var + LN_EPS);
    const float4 g4 = reinterpret_cast<const float4*>(gamma)[lane];
    const float4 be4 = reinterpret_cast<const float4*>(beta)[lane];
    float4 o;
    o.x = (hv.x - mu) * rs * g4.x + be4.x;
    o.y = (hv.y - mu) * rs * g4.y + be4.y;
    o.z = (hv.z - mu) * rs * g4.z + be4.z;
    o.w = (hv.w - mu) * rs * g4.w + be4.w;
    reinterpret_cast<float4*>(hout)[node * 64 + lane] = o;
}

extern "C" void kernel_launch(void* const* d_in, const int* in_sizes, int n_in,
                              void* d_out, int out_size, void* d_ws, size_t ws_size,
                              hipStream_t stream) {
    (void)in_sizes; (void)n_in; (void)out_size;
    const float* x         = (const float*)d_in[0];
    const int*   ei        = (const int*)d_in[1];
    const float* edge_attr = (const float*)d_in[2];
    const float* Wl        = (const float*)d_in[3];
    const float* bl        = (const float*)d_in[4];
    const float* Wr        = (const float*)d_in[5];
    const float* br        = (const float*)d_in[6];
    const float* We        = (const float*)d_in[7];
    const float* att       = (const float*)d_in[8];
    const float* bias      = (const float*)d_in[9];
    const float* gamma     = (const float*)d_in[10];
    const float* beta      = (const float*)d_in[11];

    char* ws = (char*)d_ws;
    int*   cnt     = (int*)(ws + OFF_CNT);
    int*   fill    = (int*)(ws + OFF_FILL);
    int*   row_ptr = (int*)(ws + OFF_ROWPTR);
    int*   eids    = (int*)(ws + OFF_EIDS);
    int*   srcs    = (int*)(ws + OFF_SRCS);
    int*   dsts    = (int*)(ws + OFF_DSTS);
    float* lattr   = (float*)(ws + OFF_LATTR);
    unsigned short* xlh = (unsigned short*)(ws + OFF_XLH);
    unsigned short* xrh = (unsigned short*)(ws + OFF_XRH);
    float* logits  = (float*)(ws + OFF_LOG);
    unsigned short* wlf = (unsigned short*)(ws + OFF_WLF);
    unsigned short* wrf = (unsigned short*)(ws + OFF_WRF);
    int*   inv     = (int*)(ws + OFF_INV);
    unsigned short* eap = (unsigned short*)(ws + OFF_EAP);

    float* hout      = (float*)d_out;
    float* alpha_out = (float*)d_out + N_NODES * 256;

    const bool big = (ws_size >= (size_t)WS_NEED_A);   /* constant per session */

    hipMemsetAsync(ws + OFF_CNT, 0, 2 * N_NODES * sizeof(int), stream);

    k_count<<<(N_EDGES + 255) / 256, 256, 0, stream>>>(ei, cnt);
    k_scan<<<1, 1024, 0, stream>>>(cnt, row_ptr);
    k_prep_wfrag<<<32, 256, 0, stream>>>(Wl, Wr, wlf, wrf);
    k_fill<<<(NE_TOT + 255) / 256, 256, 0, stream>>>(ei, row_ptr, fill, eids,
                                                     srcs, dsts, inv);
    k_gemm_mfma<<<N_NODES / 16, 256, 0, stream>>>(x, bl, br, wlf, wrf, xlh, xrh);
    if (big) {
        k_perm_ea<<<N_EDGES / 4, 256, 0, stream>>>(edge_attr, inv, eap);
        k_selfmean<<<N_NODES / 4, 256, 0, stream>>>(row_ptr, eids, eap);
        k_logits_mfma<true><<<2579, 256, 0, stream>>>(srcs, dsts, eap, eids,
                                                      edge_attr, lattr, xlh, xrh,
                                                      We, att, logits);
    } else {
        k_loop_attr<<<N_NODES / 4, 256, 0, stream>>>(edge_attr, row_ptr, eids, lattr);
        k_logits_mfma<false><<<2579, 256, 0, stream>>>(srcs, dsts, eap, eids,
                                                       edge_attr, lattr, xlh, xrh,
                                                       We, att, logits);
    }
    k_aggregate<<<N_NODES / 4, 256, 0, stream>>>(row_ptr, eids, srcs, logits, xlh,
                                                 bias, gamma, beta, hout, alpha_out);
}